// Round 9
// baseline (4403.391 us; speedup 1.0000x reference)
//
#include <hip/hip_runtime.h>
#include <stdint.h>

typedef unsigned short u16;
typedef unsigned int u32;
typedef __attribute__((ext_vector_type(8))) short bf16x8;
typedef __attribute__((ext_vector_type(4))) float f32x4;
typedef __attribute__((ext_vector_type(4))) unsigned int u32x4;

#define TT 1024
#define BB 64
#define EE 256
#define HH 512
#define GG 2048   // 4H

#define AS1 __attribute__((address_space(1)))
#define AS3 __attribute__((address_space(3)))

__device__ __forceinline__ float bf2f(u16 h) {
  union { u32 i; float f; } v; v.i = ((u32)h) << 16; return v.f;
}
__device__ __forceinline__ u16 f2bf(float f) {
  union { float f; u32 i; } v; v.f = f;
  u32 b = v.i;
  return (u16)((b + 0x7fffu + ((b >> 16) & 1u)) >> 16);
}
__device__ __forceinline__ float sigm(float x) {
  return 1.f / (1.f + __expf(-x));
}
__device__ __forceinline__ float tanhfast(float x) {
  float e = __expf(2.f * x);
  return 1.f - 2.f / (e + 1.f);
}
__device__ __forceinline__ int rowbad(u32x4 v, u32 e) {
  return ((((v[0] ^ e) | (v[1] ^ e)) | ((v[2] ^ e) | (v[3] ^ e))) & 0xffffu)
         != 0;
}

// r6-proven MALL-path tagged access: sc0 sc1 both ways
#define LOADS(dst, ptr)                                              \
  asm volatile("global_load_dwordx4 %0, %1, off sc0 sc1"             \
               : "=v"(dst) : "v"(ptr))
#define WAITV0                                                       \
  asm volatile("s_waitcnt vmcnt(0)" ::: "memory");                   \
  __builtin_amdgcn_sched_barrier(0)

// ---------------------------------------------------------------------------
// Kernel 1: xz[t][col][b] bf16 = (emb[x[:,t]] @ kernel) + bias, via MFMA.
// (unchanged from rounds 3-6, ~0.45 ms)
// ---------------------------------------------------------------------------
__global__ __launch_bounds__(256) void xz_gemm_mfma(
    const int* __restrict__ x, const float* __restrict__ emb,
    const float* __restrict__ Wk, const float* __restrict__ bias,
    u16* __restrict__ xz) {
  extern __shared__ char sm1[];
  bf16x8* Bl = (bf16x8*)sm1;
  __shared__ int xidx[64];
  const int tid = threadIdx.x;
  const int t = blockIdx.x;
  const int w = tid >> 6, l = tid & 63;
  if (tid < 64) xidx[tid] = x[(size_t)tid * TT + t];
  __syncthreads();

  const int row = w * 16 + (l & 15);
  const int xid = xidx[row];
  bf16x8 af[8];
#pragma unroll
  for (int ks = 0; ks < 8; ++ks) {
    int k0 = ks * 32 + ((l >> 4) << 3);
    const float4* p = (const float4*)(emb + (size_t)xid * EE + k0);
    float4 a0 = p[0], a1 = p[1];
    bf16x8 v;
    v[0] = (short)f2bf(a0.x); v[1] = (short)f2bf(a0.y);
    v[2] = (short)f2bf(a0.z); v[3] = (short)f2bf(a0.w);
    v[4] = (short)f2bf(a1.x); v[5] = (short)f2bf(a1.y);
    v[6] = (short)f2bf(a1.z); v[7] = (short)f2bf(a1.w);
    af[ks] = v;
  }

  for (int nb = 0; nb < 8; ++nb) {
    __syncthreads();
    for (int idx = tid; idx < 8192; idx += 256) {
      int nt = idx >> 9, ks = (idx >> 6) & 7, l2 = idx & 63;
      int col = nb * 256 + nt * 16 + (l2 & 15);
      int kb = ks * 32 + ((l2 >> 4) << 3);
      bf16x8 v;
#pragma unroll
      for (int j = 0; j < 8; ++j)
        v[j] = (short)f2bf(Wk[(size_t)(kb + j) * GG + col]);
      Bl[idx] = v;
    }
    __syncthreads();
#pragma unroll 2
    for (int nt = 0; nt < 16; ++nt) {
      f32x4 acc = {0.f, 0.f, 0.f, 0.f};
#pragma unroll
      for (int ks = 0; ks < 8; ++ks)
        acc = __builtin_amdgcn_mfma_f32_16x16x32_bf16(
            af[ks], Bl[(nt * 8 + ks) * 64 + l], acc, 0, 0, 0);
      int col = nb * 256 + nt * 16 + (l & 15);
      float bj = bias[col];
      int b0 = w * 16 + ((l >> 4) << 2);
      u16 o0 = f2bf(acc[0] + bj), o1 = f2bf(acc[1] + bj);
      u16 o2 = f2bf(acc[2] + bj), o3 = f2bf(acc[3] + bj);
      u32* dst = (u32*)(xz + ((size_t)t * GG + col) * BB + b0);
      dst[0] = (u32)o0 | ((u32)o1 << 16);
      dst[1] = (u32)o2 | ((u32)o3 << 16);
    }
  }
}

// ---------------------------------------------------------------------------
// Kernel 2 (round 9): r6-proven single-path tagged dataflow + r8 data plane.
// 64 WGs x 512 thr; group g = bid&7 owns batches [8g,8g+8); member r =
// bid>>3 owns units [64r,64r+64). Exchange: 4096 tagged u32 cells per
// (group,parity) in dedicated ws buffers; agent-scope relaxed stores,
// sc0+sc1 polls with tag retry (exact r6 protocol that survived 300+
// replays). MFMA is swapped-operand: z^T = R^T(A) x h(B) -> lane holds all
// 4 gates of one (b,u) in acc[0..3]; no cross-lane transpose (derivation +
// r7 behavior both confirm). ys written as coalesced per-step 16KB slices
// from staged H (time t-1 fix); ys[TT-1]/hT/cT from registers.
// ---------------------------------------------------------------------------
__global__ __launch_bounds__(512, 2) void lstm_scan9(
    const int* __restrict__ x, const float* __restrict__ h0,
    const float* __restrict__ c0, const float* __restrict__ rec,
    const u16* __restrict__ xz, float* __restrict__ out,
    u32* __restrict__ pbuf) {
  __shared__ u16 hldsA[4096];      // h(t) staged, swizzled [8 b][512 u] bf16
  __shared__ u16 hldsB[4096];
  __shared__ u32 xmask[8 * 32];
  __shared__ char ring[8 * 4096];  // xz slabs [slot][gate][unit][8b]
  const int tid = threadIdx.x;
  const int wv = tid >> 6, l = tid & 63;
  const int g = blockIdx.x & 7;
  const int r = blockIdx.x >> 3;
  const int Bg = g * 8, U0 = r * 64;

  u32* P0 = pbuf + (g * 2 + 0) * 4096;
  u32* P1 = pbuf + (g * 2 + 1) * 4096;

  // ---- geometry (swapped-operand MFMA) ----
  const int us = l >> 4;            // 0..3 (k-chunk / D-row block)
  const int n16 = l & 15;
  const int b = n16 & 7;            // batch (lanes n16>=8 duplicate 0..7)
  const bool act = n16 < 8;
  const int lu0 = wv * 8 + us;      // local unit, tile 0
  const int lu1 = lu0 + 4;          // tile 1
  const int u0g = U0 + lu0, u1g = U0 + lu1;
  const int gate_in = n16 & 3, usin = n16 >> 2;   // A-row -> (gate, uoff)

  // ---- prime xz ring slots 0..6 (waves 0-3: wave = gate) ----
  if (wv < 4) {
#pragma unroll
    for (int s = 0; s < 7; ++s)
      __builtin_amdgcn_global_load_lds(
          (AS1 const u32*)(xz + (size_t)s * GG * BB +
                           ((size_t)(wv * 512 + U0 + l)) * BB + Bg),
          (AS3 u32*)(ring + s * 4096 + wv * 1024), 16, 0, 0);
  }

  // ---- A fragments: R^T columns, 2 tiles x 16 k-steps (128 VGPRs) ----
  bf16x8 ar0[16], ar1[16];
#pragma unroll
  for (int ks = 0; ks < 16; ++ks) {
    const int kb = ks * 32 + us * 8;
    const int colA0 = gate_in * 512 + U0 + wv * 8 + usin;
    const int colA1 = colA0 + 4;
    bf16x8 v0, v1;
#pragma unroll
    for (int j = 0; j < 8; ++j) {
      v0[j] = (short)f2bf(rec[(size_t)(kb + j) * GG + colA0]);
      v1[j] = (short)f2bf(rec[(size_t)(kb + j) * GG + colA1]);
    }
    ar0[ks] = v0;
    ar1[ks] = v1;
  }

  // ---- x bitmask for group's 8 batches ----
  if (tid < 256) {
    int bb = tid >> 5, tw = tid & 31;
    u32 mword = 0;
    for (int j = 0; j < 32; ++j)
      mword |= (x[(size_t)(Bg + bb) * TT + tw * 32 + j] != 0 ? 1u : 0u) << j;
    xmask[bb * 32 + tw] = mword;
  }
  float creg0 = c0[(size_t)(Bg + b) * HH + u0g];
  float creg1 = c0[(size_t)(Bg + b) * HH + u1g];
  float hreg0 = h0[(size_t)(Bg + b) * HH + u0g];
  float hreg1 = h0[(size_t)(Bg + b) * HH + u1g];

  // ---- publish h(0): cell tid -> lu=tid>>3, b=tid&7; tag 1 ----
  {
    int lu = tid >> 3, bb = tid & 7;
    u32 cell = ((u32)f2bf(h0[(size_t)(Bg + bb) * HH + U0 + lu]) << 16) | 1u;
    __hip_atomic_store(&P0[bb * 512 + U0 + lu], cell, __ATOMIC_RELAXED,
                       __HIP_MEMORY_SCOPE_AGENT);
  }
  asm volatile("s_waitcnt vmcnt(0) lgkmcnt(0)" ::: "memory");
  __syncthreads();

  const size_t OFS1 = (size_t)BB * TT * HH;
  const size_t OFS2 = OFS1 + (size_t)BB * HH;
  u32 mw = 0;

  for (int t = 0; t < TT; ++t) {
    const u32 expect = (u32)(t + 1);
    const u32* pb = (t & 1) ? P1 : P0;
    // ---- 1. poll h(t): 8 cells/thread, tag retry (r6 cadence) ----
    u32x4 v0, v1;
    LOADS(v0, pb + 8 * tid);
    LOADS(v1, pb + 8 * tid + 4);
    WAITV0;
    while (true) {
      int bad0 = rowbad(v0, expect), bad1 = rowbad(v1, expect);
      if (!__any(bad0 | bad1)) break;
      int a0 = __any(bad0), a1 = __any(bad1);
      __builtin_amdgcn_s_sleep(1);
      if (a0) LOADS(v0, pb + 8 * tid);
      if (a1) LOADS(v1, pb + 8 * tid + 4);
      WAITV0;
    }
    // ---- 2. strip tags -> swizzled h_lds[t&1] ----
    {
      u16* H = (t & 1) ? hldsB : hldsA;
      int bb = tid >> 6, kb = tid & 63;
      bf16x8 hv;
      hv[0] = (short)(v0[0] >> 16); hv[1] = (short)(v0[1] >> 16);
      hv[2] = (short)(v0[2] >> 16); hv[3] = (short)(v0[3] >> 16);
      hv[4] = (short)(v1[0] >> 16); hv[5] = (short)(v1[1] >> 16);
      hv[6] = (short)(v1[2] >> 16); hv[7] = (short)(v1[3] >> 16);
      *(bf16x8*)&H[bb * 512 + ((kb ^ bb) << 3)] = hv;
    }
    asm volatile("s_waitcnt lgkmcnt(0)" ::: "memory");
    __builtin_amdgcn_s_barrier();
    __builtin_amdgcn_sched_barrier(0);

    // ---- 3. issue xz slab t+7 (waves 0-3) ----
    if ((t + 7 < TT) && (wv < 4))
      __builtin_amdgcn_global_load_lds(
          (AS1 const u32*)(xz + (size_t)(t + 7) * GG * BB +
                           ((size_t)(wv * 512 + U0 + l)) * BB + Bg),
          (AS3 u32*)(ring + ((t + 7) & 7) * 4096 + wv * 1024), 16, 0, 0);

    // ---- 4. B-frags (h from LDS) + MFMA ----
    const u16* H = (t & 1) ? hldsB : hldsA;
    f32x4 acc0 = {0.f, 0.f, 0.f, 0.f}, acc1 = {0.f, 0.f, 0.f, 0.f};
#pragma unroll
    for (int ks = 0; ks < 16; ++ks) {
      int kb = ks * 4 + us;
      bf16x8 hb = *(const bf16x8*)&H[b * 512 + ((kb ^ b) << 3)];
      acc0 = __builtin_amdgcn_mfma_f32_16x16x32_bf16(ar0[ks], hb, acc0,
                                                     0, 0, 0);
      acc1 = __builtin_amdgcn_mfma_f32_16x16x32_bf16(ar1[ks], hb, acc1,
                                                     0, 0, 0);
    }

    // ---- 5. xz + mask + gates (acc[reg] = gate reg; no transpose) ----
    if ((t & 31) == 0) mw = xmask[b * 32 + (t >> 5)];
    const bool m = (mw >> (t & 31)) & 1;
    const char* slab = ring + (t & 7) * 4096;
    float ho0, ho1, co0, co1;
    {
      float zi = acc0[0] + bf2f(*(const u16*)(slab + 0 * 1024 + lu0 * 16 + b * 2));
      float zf = acc0[1] + bf2f(*(const u16*)(slab + 1 * 1024 + lu0 * 16 + b * 2));
      float zg = acc0[2] + bf2f(*(const u16*)(slab + 2 * 1024 + lu0 * 16 + b * 2));
      float zo = acc0[3] + bf2f(*(const u16*)(slab + 3 * 1024 + lu0 * 16 + b * 2));
      float ig = sigm(zi), fg = sigm(zf), gv = tanhfast(zg), og = sigm(zo);
      float cn = fg * creg0 + ig * gv;
      float hn = og * tanhfast(cn);
      ho0 = m ? hn : hreg0; co0 = m ? cn : creg0;
      creg0 = co0; hreg0 = ho0;
    }
    {
      float zi = acc1[0] + bf2f(*(const u16*)(slab + 0 * 1024 + lu1 * 16 + b * 2));
      float zf = acc1[1] + bf2f(*(const u16*)(slab + 1 * 1024 + lu1 * 16 + b * 2));
      float zg = acc1[2] + bf2f(*(const u16*)(slab + 2 * 1024 + lu1 * 16 + b * 2));
      float zo = acc1[3] + bf2f(*(const u16*)(slab + 3 * 1024 + lu1 * 16 + b * 2));
      float ig = sigm(zi), fg = sigm(zf), gv = tanhfast(zg), og = sigm(zo);
      float cn = fg * creg1 + ig * gv;
      float hn = og * tanhfast(cn);
      ho1 = m ? hn : hreg1; co1 = m ? cn : creg1;
      creg1 = co1; hreg1 = ho1;
    }

    // ---- 6. publish h(t+1) (critical path) / final outputs ----
    if (t < TT - 1) {
      const u32 ntag = (u32)(t + 2);
      u32* pn = (t & 1) ? P0 : P1;
      if (act) {
        u32 cell0 = ((u32)f2bf(ho0) << 16) | ntag;
        u32 cell1 = ((u32)f2bf(ho1) << 16) | ntag;
        __hip_atomic_store(&pn[b * 512 + u0g], cell0, __ATOMIC_RELAXED,
                           __HIP_MEMORY_SCOPE_AGENT);
        __hip_atomic_store(&pn[b * 512 + u1g], cell1, __ATOMIC_RELAXED,
                           __HIP_MEMORY_SCOPE_AGENT);
      }
    } else if (act) {
      // ys[TT-1] from registers (slice path covers 0..TT-2), plus hT, cT
      out[((size_t)(Bg + b) * TT + (TT - 1)) * HH + u0g] = ho0;
      out[((size_t)(Bg + b) * TT + (TT - 1)) * HH + u1g] = ho1;
      out[OFS1 + (size_t)(Bg + b) * HH + u0g] = ho0;
      out[OFS1 + (size_t)(Bg + b) * HH + u1g] = ho1;
      out[OFS2 + (size_t)(Bg + b) * HH + u0g] = co0;
      out[OFS2 + (size_t)(Bg + b) * HH + u1g] = co1;
    }

    // ---- 7. coalesced ys slice from H = h(t) = ys[t-1] ----
    if (t > 0 && (((t - 1) & 7) == r)) {
      int bb = tid >> 6, kb = tid & 63;
      const bf16x8 hv = *(const bf16x8*)&H[bb * 512 + ((kb ^ bb) << 3)];
      float o8[8];
#pragma unroll
      for (int j = 0; j < 8; ++j) o8[j] = bf2f((u16)hv[j]);
      float* dst = out + ((size_t)(Bg + bb) * TT + (t - 1)) * HH + kb * 8;
      *(f32x4*)dst = *(const f32x4*)&o8[0];
      *(f32x4*)(dst + 4) = *(const f32x4*)&o8[4];
    }
  }
}

// ---------------------------------------------------------------------------
extern "C" void kernel_launch(void* const* d_in, const int* in_sizes, int n_in,
                              void* d_out, int out_size, void* d_ws,
                              size_t ws_size, hipStream_t stream) {
  const int* x = (const int*)d_in[0];
  const float* h0 = (const float*)d_in[1];
  const float* c0 = (const float*)d_in[2];
  const float* emb = (const float*)d_in[3];
  const float* Wk = (const float*)d_in[4];
  const float* rec = (const float*)d_in[5];
  const float* bias = (const float*)d_in[6];
  float* out = (float*)d_out;
  char* ws = (char*)d_ws;

  const size_t XZ_BYTES = (size_t)TT * GG * BB * 2;  // 256 MiB
  u16* xz = (u16*)ws;
  u32* pbuf = (u32*)(ws + XZ_BYTES);   // 256 KB exchange buffers
  if (ws_size < XZ_BYTES + 262144) return;

  // zero exchange buffers each launch (kills cross-replay stale tags)
  hipMemsetAsync(pbuf, 0, 262144, stream);

  hipFuncSetAttribute((const void*)xz_gemm_mfma,
                      hipFuncAttributeMaxDynamicSharedMemorySize, 131072);
  xz_gemm_mfma<<<TT, 256, 131072, stream>>>(x, emb, Wk, bias, xz);

  lstm_scan9<<<64, 512, 0, stream>>>(x, h0, c0, rec, xz, out, pbuf);
}

// Round 10
// 3626.054 us; speedup vs baseline: 1.2144x; 1.2144x over previous
//
#include <hip/hip_runtime.h>
#include <stdint.h>

typedef unsigned short u16;
typedef unsigned int u32;
typedef __attribute__((ext_vector_type(8))) short bf16x8;
typedef __attribute__((ext_vector_type(4))) float f32x4;
typedef __attribute__((ext_vector_type(4))) unsigned int u32x4;
typedef __attribute__((ext_vector_type(2))) unsigned int u32x2;

#define TT 1024
#define BB 64
#define EE 256
#define HH 512
#define GG 2048   // 4H

#define AS1 __attribute__((address_space(1)))
#define AS3 __attribute__((address_space(3)))

__device__ __forceinline__ float bf2f(u16 h) {
  union { u32 i; float f; } v; v.i = ((u32)h) << 16; return v.f;
}
__device__ __forceinline__ u16 f2bf(float f) {
  union { float f; u32 i; } v; v.f = f;
  u32 b = v.i;
  return (u16)((b + 0x7fffu + ((b >> 16) & 1u)) >> 16);
}
__device__ __forceinline__ float sigm(float x) {
  return 1.f / (1.f + __expf(-x));
}
__device__ __forceinline__ float tanhfast(float x) {
  float e = __expf(2.f * x);
  return 1.f - 2.f / (e + 1.f);
}
// cell position in 4096-cell group buffer (8 batches x 512 units)
__device__ __forceinline__ int cellpos8(int bl, int u) {
  return ((u >> 5) * 32 + ((bl & 7) | (((u >> 3) & 3) << 3))) * 8 + (u & 7);
}
__device__ __forceinline__ int rowbad(u32x4 v, u32 e) {
  return ((((v[0] ^ e) | (v[1] ^ e)) | ((v[2] ^ e) | (v[3] ^ e))) & 0xffffu)
         != 0;
}

#define LOADF(dst, ptr)                                              \
  asm volatile("global_load_dwordx4 %0, %1, off sc0"                 \
               : "=v"(dst) : "v"(ptr))
#define LOADS(dst, ptr)                                              \
  asm volatile("global_load_dwordx4 %0, %1, off sc0 sc1"             \
               : "=v"(dst) : "v"(ptr))
#define WAITV0                                                       \
  asm volatile("s_waitcnt vmcnt(0)" ::: "memory");                   \
  __builtin_amdgcn_sched_barrier(0)

// ---------------------------------------------------------------------------
// Kernel 1: xz[t][col][b] bf16 = (emb[x[:,t]] @ kernel) + bias, via MFMA.
// (unchanged from rounds 3-9, ~0.45 ms)
// ---------------------------------------------------------------------------
__global__ __launch_bounds__(256) void xz_gemm_mfma(
    const int* __restrict__ x, const float* __restrict__ emb,
    const float* __restrict__ Wk, const float* __restrict__ bias,
    u16* __restrict__ xz) {
  extern __shared__ char sm1[];
  bf16x8* Bl = (bf16x8*)sm1;
  __shared__ int xidx[64];
  const int tid = threadIdx.x;
  const int t = blockIdx.x;
  const int w = tid >> 6, l = tid & 63;
  if (tid < 64) xidx[tid] = x[(size_t)tid * TT + t];
  __syncthreads();

  const int row = w * 16 + (l & 15);
  const int xid = xidx[row];
  bf16x8 af[8];
#pragma unroll
  for (int ks = 0; ks < 8; ++ks) {
    int k0 = ks * 32 + ((l >> 4) << 3);
    const float4* p = (const float4*)(emb + (size_t)xid * EE + k0);
    float4 a0 = p[0], a1 = p[1];
    bf16x8 v;
    v[0] = (short)f2bf(a0.x); v[1] = (short)f2bf(a0.y);
    v[2] = (short)f2bf(a0.z); v[3] = (short)f2bf(a0.w);
    v[4] = (short)f2bf(a1.x); v[5] = (short)f2bf(a1.y);
    v[6] = (short)f2bf(a1.z); v[7] = (short)f2bf(a1.w);
    af[ks] = v;
  }

  for (int nb = 0; nb < 8; ++nb) {
    __syncthreads();
    for (int idx = tid; idx < 8192; idx += 256) {
      int nt = idx >> 9, ks = (idx >> 6) & 7, l2 = idx & 63;
      int col = nb * 256 + nt * 16 + (l2 & 15);
      int kb = ks * 32 + ((l2 >> 4) << 3);
      bf16x8 v;
#pragma unroll
      for (int j = 0; j < 8; ++j)
        v[j] = (short)f2bf(Wk[(size_t)(kb + j) * GG + col]);
      Bl[idx] = v;
    }
    __syncthreads();
#pragma unroll 2
    for (int nt = 0; nt < 16; ++nt) {
      f32x4 acc = {0.f, 0.f, 0.f, 0.f};
#pragma unroll
      for (int ks = 0; ks < 8; ++ks)
        acc = __builtin_amdgcn_mfma_f32_16x16x32_bf16(
            af[ks], Bl[(nt * 8 + ks) * 64 + l], acc, 0, 0, 0);
      int col = nb * 256 + nt * 16 + (l & 15);
      float bj = bias[col];
      int b0 = w * 16 + ((l >> 4) << 2);
      u16 o0 = f2bf(acc[0] + bj), o1 = f2bf(acc[1] + bj);
      u16 o2 = f2bf(acc[2] + bj), o3 = f2bf(acc[3] + bj);
      u32* dst = (u32*)(xz + ((size_t)t * GG + col) * BB + b0);
      dst[0] = (u32)o0 | ((u32)o1 << 16);
      dst[1] = (u32)o2 | ((u32)o3 << 16);
    }
  }
}

// ---------------------------------------------------------------------------
// Kernel 2 (round 10): r6 VERBATIM protocol (dual fast+slow tagged cells,
// group g = bid&7 -> co-XCD members under round-robin), with 3 deltas:
//   1. patient fast polling: slow-merge onset at 6 tries (was 3) so natural
//      inter-WG skew doesn't trigger MALL merges when local L2 would hit.
//   2. per-step scattered out stores -> coalesced 16KB slice per group per
//      step, written from staged A_lds (H(t) = ys[t-1]); WG r writes
//      (t-1)%8==r.
//   3. final step writes ys[TT-1]/hT/cT from registers.
// Everything else (geometry, dance, ring, publish, strip) is round-6 code.
// ---------------------------------------------------------------------------
__global__ __launch_bounds__(512, 2) void lstm_scan10(
    const int* __restrict__ x, const float* __restrict__ h0,
    const float* __restrict__ c0, const float* __restrict__ rec,
    const u16* __restrict__ xz, float* __restrict__ out,
    u32* __restrict__ fastb, u32* __restrict__ slowb) {
  extern __shared__ char sm2[];
  u16* A0 = (u16*)sm2;                 // 8 KB (4096 cells)
  u16* A1 = (u16*)(sm2 + 8192);        // 8 KB
  u32* xmask = (u32*)(sm2 + 16384);    // 1 KB [8][32]
  char* ring = sm2 + 17408;            // 8 slots * 4 KB = 32 KB
  const int tid = threadIdx.x;
  const int wv = tid >> 6, l = tid & 63;
  const int g = blockIdx.x & 7;
  const int r = blockIdx.x >> 3;
  const int Bg = g * 8;
  const int U0 = r * 64;
  const int q = l & 3;
  const int uoff = (l >> 2) & 3;
  const int u0g = U0 + 8 * wv + uoff;
  const int u1g = u0g + 4;
  const int col0 = q * 512 + u0g;
  const int col1 = q * 512 + u1g;
  const int bl = ((l >> 4) << 2) + q;   // 0..15, valid <8 iff l<32
  const int blc = bl & 7;
  const bool act = (l < 32);
  const int b = Bg + blc;
  u32* FP0 = fastb + (g * 2 + 0) * 4096;
  u32* FP1 = fastb + (g * 2 + 1) * 4096;
  u32* SP0 = slowb + (g * 2 + 0) * 4096;
  u32* SP1 = slowb + (g * 2 + 1) * 4096;

  // prime xz ring slots 0..6 (waves 0-3: wave wv stages gate wv, cols U0+l)
  const size_t gofs = ((size_t)(wv * 512 + U0 + l)) * BB + Bg;
  if (wv < 4) {
#pragma unroll
    for (int s = 0; s < 7; ++s)
      __builtin_amdgcn_global_load_lds(
          (AS1 const u32*)(xz + (size_t)s * GG * BB + gofs),
          (AS3 u32*)(ring + s * 4096 + wv * 1024), 16, 0, 0);
  }

  // --- B fragments (R slice) into registers, once ---
  bf16x8 bfr0[16], bfr1[16];
#pragma unroll
  for (int ks = 0; ks < 16; ++ks) {
    int kbase = ks * 32 + ((l >> 4) << 3);
#pragma unroll
    for (int j = 0; j < 8; ++j) {
      bfr0[ks][j] = (short)f2bf(rec[(size_t)(kbase + j) * GG + col0]);
      bfr1[ks][j] = (short)f2bf(rec[(size_t)(kbase + j) * GG + col1]);
    }
  }
  // --- x bitmask for group's 8 batches ---
  if (tid < 256) {
    int bb = tid >> 5, tw = tid & 31;
    u32 mword = 0;
    for (int j = 0; j < 32; ++j)
      mword |= (x[(size_t)(Bg + bb) * TT + tw * 32 + j] != 0 ? 1u : 0u) << j;
    xmask[bb * 32 + tw] = mword;
  }
  float creg0 = c0[(size_t)b * HH + u0g];
  float creg1 = c0[(size_t)b * HH + u1g];
  float hreg0 = h0[(size_t)b * HH + u0g];
  float hreg1 = h0[(size_t)b * HH + u1g];
  // drain prime glls + loads before barrier
  asm volatile("s_waitcnt vmcnt(0) lgkmcnt(0)" ::: "memory");
  __syncthreads();

  // --- publish h(0): 512 cells/WG, tag 1, dual copy ---
  {
    int uu = tid >> 3, bl2 = tid & 7;
    u32 cell = ((u32)f2bf(h0[(size_t)(Bg + bl2) * HH + U0 + uu]) << 16) | 1u;
    int wp = cellpos8(bl2, U0 + uu);
    __hip_atomic_store(&FP0[wp], cell, __ATOMIC_RELAXED,
                       __HIP_MEMORY_SCOPE_WORKGROUP);
    __hip_atomic_store(&SP0[wp], cell, __ATOMIC_RELAXED,
                       __HIP_MEMORY_SCOPE_AGENT);
  }

  const size_t OFS1 = (size_t)BB * TT * HH;
  const size_t OFS2 = OFS1 + (size_t)BB * HH;
  const int pair = (l & 7) | ((l >> 4) << 3);
  u32 mw = 0;

  for (int t = 0; t < TT; ++t) {
    // ---- 1. xz + mask for this step from ring (independent of h) ----
    if ((t & 31) == 0) mw = xmask[blc * 32 + (t >> 5)];
    const bool m = (mw >> (t & 31)) & 1;
    const char* slab = ring + (t & 7) * 4096;
    float xzv[8];
#pragma unroll
    for (int q2 = 0; q2 < 4; ++q2) {
      xzv[q2] = bf2f(*(const u16*)(slab + q2 * 1024 + (8 * wv + uoff) * 16 +
                                   blc * 2));
      xzv[4 + q2] = bf2f(*(const u16*)(slab + q2 * 1024 +
                                       (8 * wv + uoff + 4) * 16 + blc * 2));
    }

    // ---- 2. stage h(t): patient fast poll, slow merge from try 6 ----
    const u32 expect = (u32)(t + 1) & 0xffffu;
    const u32* fb = (t & 1) ? FP1 : FP0;
    const u32* sb = (t & 1) ? SP1 : SP0;
    u32x4 v0, v1;
    LOADF(v0, fb + 8 * tid);
    LOADF(v1, fb + 8 * tid + 4);
    WAITV0;
    int tries = 0;
    while (true) {
      int bad0 = rowbad(v0, expect), bad1 = rowbad(v1, expect);
      if (!__any(bad0 | bad1)) break;
      int a0 = __any(bad0), a1 = __any(bad1);
      __builtin_amdgcn_s_sleep(1);
      ++tries;
      if (a0) LOADF(v0, fb + 8 * tid);
      if (a1) LOADF(v1, fb + 8 * tid + 4);
      if (tries >= 6) {
        u32x4 s0, s1;
        if (a0) LOADS(s0, sb + 8 * tid);
        if (a1) LOADS(s1, sb + 8 * tid + 4);
        WAITV0;
        if (a0 && !rowbad(s0, expect)) v0 = s0;
        if (a1 && !rowbad(s1, expect)) v1 = s1;
      } else {
        WAITV0;
      }
    }
    // ---- 3. strip tags -> ping-pong A_lds; one barrier ----
    u16* Ac = (t & 1) ? A1 : A0;
    {
      u32x4 dd;
      dd[0] = (v0[0] >> 16) | (v0[1] & 0xffff0000u);
      dd[1] = (v0[2] >> 16) | (v0[3] & 0xffff0000u);
      dd[2] = (v1[0] >> 16) | (v1[1] & 0xffff0000u);
      dd[3] = (v1[2] >> 16) | (v1[3] & 0xffff0000u);
      *(u32x4*)&Ac[8 * tid] = dd;
    }
    asm volatile("s_waitcnt lgkmcnt(0)" ::: "memory");
    __builtin_amdgcn_s_barrier();
    __builtin_amdgcn_sched_barrier(0);

    // ---- 4. issue xz slab t+7 ----
    if ((t + 7 < TT) && (wv < 4))
      __builtin_amdgcn_global_load_lds(
          (AS1 const u32*)(xz + (size_t)(t + 7) * GG * BB + gofs),
          (AS3 u32*)(ring + ((t + 7) & 7) * 4096 + wv * 1024), 16, 0, 0);

    // ---- 5. A frags + MFMA ----
    bf16x8 af[16];
#pragma unroll
    for (int ks = 0; ks < 16; ++ks)
      af[ks] = *(const bf16x8*)&Ac[(ks * 32 + pair) * 8];
    f32x4 acc0 = {0.f, 0.f, 0.f, 0.f}, acc1 = {0.f, 0.f, 0.f, 0.f};
#pragma unroll
    for (int ks = 0; ks < 16; ++ks) {
      acc0 = __builtin_amdgcn_mfma_f32_16x16x32_bf16(af[ks], bfr0[ks], acc0,
                                                     0, 0, 0);
      acc1 = __builtin_amdgcn_mfma_f32_16x16x32_bf16(af[ks], bfr1[ks], acc1,
                                                     0, 0, 0);
    }

    u32* fn = (t & 1) ? FP0 : FP1;
    u32* sn = (t & 1) ? SP0 : SP1;
    const u32 ntag = (u32)(t + 2) & 0xffffu;
    float hosave[2], cosave[2];

    // ---- 6. transpose dance + gates (r6 verbatim) ----
#pragma unroll
    for (int ti = 0; ti < 2; ++ti) {
      f32x4 acc = ti ? acc1 : acc0;
      float accLo = (q & 1) ? acc[1] : acc[0];
      float accHi = (q & 1) ? acc[3] : acc[2];
      float sendA = (q & 1) ? acc[0] : acc[1];
      float recvA = __shfl_xor(sendA, 1);
      float sendB = (q & 1) ? acc[2] : acc[3];
      float recvB = __shfl_xor(sendB, 1);
      float k1 = (q & 2) ? accHi : accLo;
      float s2A = (q & 2) ? accLo : accHi;
      float r2A = __shfl_xor(s2A, 2);
      float k2 = (q & 2) ? recvB : recvA;
      float s2B = (q & 2) ? recvA : recvB;
      float r2B = __shfl_xor(s2B, 2);
      float p1 = (q & 1) ? k2 : k1;
      float p2 = (q & 1) ? k1 : k2;
      float p3 = (q & 1) ? r2B : r2A;
      float p4 = (q & 1) ? r2A : r2B;
      float W0 = (q & 2) ? p3 : p1;
      float W1 = (q & 2) ? p4 : p2;
      float W2 = (q & 2) ? p1 : p3;
      float W3 = (q & 2) ? p2 : p4;
      float z0 = W0 + xzv[ti ? 4 : 0];
      float z1 = W1 + xzv[ti ? 5 : 1];
      float z2 = W2 + xzv[ti ? 6 : 2];
      float z3 = W3 + xzv[ti ? 7 : 3];
      float ig = sigm(z0), fg = sigm(z1), gg = tanhfast(z2), og = sigm(z3);
      float cprev = ti ? creg1 : creg0;
      float hprev = ti ? hreg1 : hreg0;
      float cn = fg * cprev + ig * gg;
      float hn = og * tanhfast(cn);
      float ho = m ? hn : hprev;
      float co = m ? cn : cprev;
      if (ti) { creg1 = co; hreg1 = ho; } else { creg0 = co; hreg0 = ho; }
      hosave[ti] = ho; cosave[ti] = co;
      // publish immediately (critical path): dual copy
      if (act && t < TT - 1) {
        const int u = ti ? u1g : u0g;
        u32 cell = ((u32)f2bf(ho) << 16) | ntag;
        int wp = cellpos8(blc, u);
        __hip_atomic_store(&fn[wp], cell, __ATOMIC_RELAXED,
                           __HIP_MEMORY_SCOPE_WORKGROUP);
        __hip_atomic_store(&sn[wp], cell, __ATOMIC_RELAXED,
                           __HIP_MEMORY_SCOPE_AGENT);
      }
    }
    // ---- 7. outputs: final step from registers ----
    if (t == TT - 1 && act) {
      out[((size_t)b * TT + (TT - 1)) * HH + u0g] = hosave[0];
      out[((size_t)b * TT + (TT - 1)) * HH + u1g] = hosave[1];
      out[OFS1 + (size_t)b * HH + u0g] = hosave[0];
      out[OFS1 + (size_t)b * HH + u1g] = hosave[1];
      out[OFS2 + (size_t)b * HH + u0g] = cosave[0];
      out[OFS2 + (size_t)b * HH + u1g] = cosave[1];
    }
    // ---- 8. coalesced ys slice from Ac = h(t) = ys[t-1] ----
    if (t > 0 && (((t - 1) & 7) == r)) {
      int b2 = tid >> 6, k = tid & 63;
      int cb = ((k >> 2) << 8) + ((b2 + ((k & 3) << 3)) << 3);
      const bf16x8 hv = *(const bf16x8*)&Ac[cb];
      float o8[8];
#pragma unroll
      for (int j = 0; j < 8; ++j) o8[j] = bf2f((u16)hv[j]);
      float* dst = out + ((size_t)(Bg + b2) * TT + (t - 1)) * HH + k * 8;
      *(f32x4*)dst = *(const f32x4*)&o8[0];
      *(f32x4*)(dst + 4) = *(const f32x4*)&o8[4];
    }
  }
}

// ---------------------------------------------------------------------------
extern "C" void kernel_launch(void* const* d_in, const int* in_sizes, int n_in,
                              void* d_out, int out_size, void* d_ws,
                              size_t ws_size, hipStream_t stream) {
  const int* x = (const int*)d_in[0];
  const float* h0 = (const float*)d_in[1];
  const float* c0 = (const float*)d_in[2];
  const float* emb = (const float*)d_in[3];
  const float* Wk = (const float*)d_in[4];
  const float* rec = (const float*)d_in[5];
  const float* bias = (const float*)d_in[6];
  float* out = (float*)d_out;
  char* ws = (char*)d_ws;

  const size_t XZ_BYTES = (size_t)TT * GG * BB * 2;  // 256 MiB
  u16* xz = (u16*)ws;
  u32* fastb = (u32*)(ws + XZ_BYTES);            // 256 KB
  u32* slowb = (u32*)(ws + XZ_BYTES + 262144);   // 256 KB
  if (ws_size < XZ_BYTES + 524288) return;       // proven available (r6)

  // zero exchange buffers each launch (kills cross-replay stale tags)
  hipMemsetAsync(fastb, 0, 524288, stream);

  hipFuncSetAttribute((const void*)xz_gemm_mfma,
                      hipFuncAttributeMaxDynamicSharedMemorySize, 131072);
  xz_gemm_mfma<<<TT, 256, 131072, stream>>>(x, emb, Wk, bias, xz);

  hipFuncSetAttribute((const void*)lstm_scan10,
                      hipFuncAttributeMaxDynamicSharedMemorySize, 50176);
  lstm_scan10<<<64, 512, 50176, stream>>>(x, h0, c0, rec, xz, out, fastb,
                                          slowb);
}

// Round 11
// 3448.527 us; speedup vs baseline: 1.2769x; 1.0515x over previous
//
#include <hip/hip_runtime.h>
#include <stdint.h>

typedef unsigned short u16;
typedef unsigned int u32;
typedef __attribute__((ext_vector_type(8))) short bf16x8;
typedef __attribute__((ext_vector_type(4))) float f32x4;
typedef __attribute__((ext_vector_type(4))) unsigned int u32x4;
typedef __attribute__((ext_vector_type(2))) unsigned int u32x2;

#define TT 1024
#define BB 64
#define EE 256
#define HH 512
#define GG 2048   // 4H

#define AS1 __attribute__((address_space(1)))
#define AS3 __attribute__((address_space(3)))

__device__ __forceinline__ float bf2f(u16 h) {
  union { u32 i; float f; } v; v.i = ((u32)h) << 16; return v.f;
}
__device__ __forceinline__ u16 f2bf(float f) {
  union { float f; u32 i; } v; v.f = f;
  u32 b = v.i;
  return (u16)((b + 0x7fffu + ((b >> 16) & 1u)) >> 16);
}
__device__ __forceinline__ float sigm(float x) {
  return 1.f / (1.f + __expf(-x));
}
__device__ __forceinline__ float tanhfast(float x) {
  float e = __expf(2.f * x);
  return 1.f - 2.f / (e + 1.f);
}
__device__ __forceinline__ int cellpos8(int bl, int u) {
  return ((u >> 5) * 32 + ((bl & 7) | (((u >> 3) & 3) << 3))) * 8 + (u & 7);
}
__device__ __forceinline__ int rowbad(u32x4 v, u32 e) {
  return ((((v[0] ^ e) | (v[1] ^ e)) | ((v[2] ^ e) | (v[3] ^ e))) & 0xffffu)
         != 0;
}

#define LOADF(dst, ptr)                                              \
  asm volatile("global_load_dwordx4 %0, %1, off sc0"                 \
               : "=v"(dst) : "v"(ptr))
#define LOADS(dst, ptr)                                              \
  asm volatile("global_load_dwordx4 %0, %1, off sc0 sc1"             \
               : "=v"(dst) : "v"(ptr))
#define WAITV0                                                       \
  asm volatile("s_waitcnt vmcnt(0)" ::: "memory");                   \
  __builtin_amdgcn_sched_barrier(0)

// ---------------------------------------------------------------------------
// Kernel 0a: emb f32 -> bf16 (12.8M elems). One-time per launch.
// ---------------------------------------------------------------------------
__global__ __launch_bounds__(256) void conv_emb(const float* __restrict__ emb,
                                                u16* __restrict__ embbf) {
  int i = blockIdx.x * 256 + threadIdx.x;   // 12500*256 = 3.2M quads
  float4 v = ((const float4*)emb)[i];
  u32x2 p;
  p[0] = (u32)f2bf(v.x) | ((u32)f2bf(v.y) << 16);
  p[1] = (u32)f2bf(v.z) | ((u32)f2bf(v.w) << 16);
  ((u32x2*)embbf)[i] = p;
}

// ---------------------------------------------------------------------------
// Kernel 0b: pack Wk (f32 [K=256][2048]) into MFMA B-fragment order bf16:
// wkp[((ct*8+ks)*64 + lane)*8 + j] = bf16(Wk[(ks*32+(lane>>4)*8+j)][ct*16+(lane&15)])
// ---------------------------------------------------------------------------
__global__ __launch_bounds__(256) void pack_wk(const float* __restrict__ Wk,
                                               u16* __restrict__ wkp) {
  int idx = blockIdx.x * 256 + threadIdx.x;   // 256 blocks -> 65536
  int ct = idx >> 9, ks = (idx >> 6) & 7, l = idx & 63;
  int col = ct * 16 + (l & 15);
  int kb = ks * 32 + ((l >> 4) << 3);
  u32x4 p;
#pragma unroll
  for (int h = 0; h < 4; ++h) {
    u16 a = f2bf(Wk[(size_t)(kb + 2 * h) * GG + col]);
    u16 b = f2bf(Wk[(size_t)(kb + 2 * h + 1) * GG + col]);
    p[h] = (u32)a | ((u32)b << 16);
  }
  *(u32x4*)&wkp[(size_t)idx * 8] = p;
}

// ---------------------------------------------------------------------------
// Kernel 1 (new): xz GEMM from pre-packed bf16. 512 WGs x 512 thr.
// WG = (colblock cb 0..7 [256 cols], tgroup tg 0..63 [16 t]). B slice
// (128 KB frag-order) staged once via global_load_lds, reused 16 t.
// Wave = (mtile mt 0..3, nhalf nh 0..1). 1024 MFMA/wave.
// ---------------------------------------------------------------------------
__global__ __launch_bounds__(512) void xz_gemm2(
    const int* __restrict__ x, const u16* __restrict__ embbf,
    const u16* __restrict__ wkp, const float* __restrict__ bias,
    u16* __restrict__ xz) {
  extern __shared__ char smg[];          // 128 KB B frags
  __shared__ int xidx[16][64];
  __shared__ float biasl[256];
  const int tid = threadIdx.x;
  const int wv = tid >> 6, l = tid & 63;
  const int cb = blockIdx.x & 7;
  const int tg = blockIdx.x >> 3;
  const int mt = wv & 3, nh = wv >> 2;

  // stage B: 16 iters x (8 waves x 64 lanes x 16B)
#pragma unroll
  for (int i = 0; i < 16; ++i)
    __builtin_amdgcn_global_load_lds(
        (AS1 const u32*)(wkp + ((size_t)cb * 65536) +
                         (size_t)(((i * 8 + wv) * 64) + l) * 8),
        (AS3 u32*)(smg + ((i * 8 + wv) << 10)), 16, 0, 0);
  if (tid < 256) {
    int b = tid >> 2, k4 = (tid & 3) << 2;
    int4 v = *(const int4*)&x[(size_t)b * TT + tg * 16 + k4];
    xidx[k4 + 0][b] = v.x; xidx[k4 + 1][b] = v.y;
    xidx[k4 + 2][b] = v.z; xidx[k4 + 3][b] = v.w;
    biasl[tid] = bias[cb * 256 + tid];
  }
  __syncthreads();

  const int row = mt * 16 + (l & 15);
  const int b0 = mt * 16 + ((l >> 4) << 2);
  for (int tl = 0; tl < 16; ++tl) {
    const int xid = xidx[tl][row];
    bf16x8 af[8];
#pragma unroll
    for (int ks = 0; ks < 8; ++ks)
      af[ks] = *(const bf16x8*)&embbf[(size_t)xid * EE + ks * 32 +
                                      ((l >> 4) << 3)];
    const int t = tg * 16 + tl;
#pragma unroll
    for (int nt = 0; nt < 8; ++nt) {
      const int ctl = nh * 8 + nt;
      f32x4 acc = {0.f, 0.f, 0.f, 0.f};
#pragma unroll
      for (int ks = 0; ks < 8; ++ks)
        acc = __builtin_amdgcn_mfma_f32_16x16x32_bf16(
            af[ks], *(const bf16x8*)(smg + (((ctl * 8 + ks) * 64 + l) << 4)),
            acc, 0, 0, 0);
      const int col = cb * 256 + ctl * 16 + (l & 15);
      const float bj = biasl[ctl * 16 + (l & 15)];
      u16 o0 = f2bf(acc[0] + bj), o1 = f2bf(acc[1] + bj);
      u16 o2 = f2bf(acc[2] + bj), o3 = f2bf(acc[3] + bj);
      u32* dst = (u32*)(xz + ((size_t)t * GG + col) * BB + b0);
      dst[0] = (u32)o0 | ((u32)o1 << 16);
      dst[1] = (u32)o2 | ((u32)o3 << 16);
    }
  }
}

// ---------------------------------------------------------------------------
// Kernel 1-fallback: round-3..6 gemm (f32 inputs, converts inline). Used
// only if ws too small for the preconvert buffers.
// ---------------------------------------------------------------------------
__global__ __launch_bounds__(256) void xz_gemm_mfma(
    const int* __restrict__ x, const float* __restrict__ emb,
    const float* __restrict__ Wk, const float* __restrict__ bias,
    u16* __restrict__ xz) {
  extern __shared__ char sm1[];
  bf16x8* Bl = (bf16x8*)sm1;
  __shared__ int xidx[64];
  const int tid = threadIdx.x;
  const int t = blockIdx.x;
  const int w = tid >> 6, l = tid & 63;
  if (tid < 64) xidx[tid] = x[(size_t)tid * TT + t];
  __syncthreads();
  const int row = w * 16 + (l & 15);
  const int xid = xidx[row];
  bf16x8 af[8];
#pragma unroll
  for (int ks = 0; ks < 8; ++ks) {
    int k0 = ks * 32 + ((l >> 4) << 3);
    const float4* p = (const float4*)(emb + (size_t)xid * EE + k0);
    float4 a0 = p[0], a1 = p[1];
    bf16x8 v;
    v[0] = (short)f2bf(a0.x); v[1] = (short)f2bf(a0.y);
    v[2] = (short)f2bf(a0.z); v[3] = (short)f2bf(a0.w);
    v[4] = (short)f2bf(a1.x); v[5] = (short)f2bf(a1.y);
    v[6] = (short)f2bf(a1.z); v[7] = (short)f2bf(a1.w);
    af[ks] = v;
  }
  for (int nb = 0; nb < 8; ++nb) {
    __syncthreads();
    for (int idx = tid; idx < 8192; idx += 256) {
      int nt = idx >> 9, ks = (idx >> 6) & 7, l2 = idx & 63;
      int col = nb * 256 + nt * 16 + (l2 & 15);
      int kb = ks * 32 + ((l2 >> 4) << 3);
      bf16x8 v;
#pragma unroll
      for (int j = 0; j < 8; ++j)
        v[j] = (short)f2bf(Wk[(size_t)(kb + j) * GG + col]);
      Bl[idx] = v;
    }
    __syncthreads();
#pragma unroll 2
    for (int nt = 0; nt < 16; ++nt) {
      f32x4 acc = {0.f, 0.f, 0.f, 0.f};
#pragma unroll
      for (int ks = 0; ks < 8; ++ks)
        acc = __builtin_amdgcn_mfma_f32_16x16x32_bf16(
            af[ks], Bl[(nt * 8 + ks) * 64 + l], acc, 0, 0, 0);
      int col = nb * 256 + nt * 16 + (l & 15);
      float bj = bias[col];
      int b0 = w * 16 + ((l >> 4) << 2);
      u16 o0 = f2bf(acc[0] + bj), o1 = f2bf(acc[1] + bj);
      u16 o2 = f2bf(acc[2] + bj), o3 = f2bf(acc[3] + bj);
      u32* dst = (u32*)(xz + ((size_t)t * GG + col) * BB + b0);
      dst[0] = (u32)o0 | ((u32)o1 << 16);
      dst[1] = (u32)o2 | ((u32)o3 << 16);
    }
  }
}

// ---------------------------------------------------------------------------
// Kernel 2 (round 11): r6 protocol + per-chunk dataflow pipeline.
// Layout fact (r6): wave wv's 8 polled cells ARE producer-WG wv's chunk
// (k-steps 2wv,2wv+1). Change vs r6: after strip, wave releases LDS flag
// flg[parity][wv]=t+1; consumer waves spin per-chunk (acquire) and MFMA
// chunks as they arrive (split accumulators halve chains). One s_barrier
// at END of step (LDS ping-pong reuse only; off the publish path).
// Everything else (dual publish, poll cadence onset 3, dance, ring,
// scattered nontemporal outs) is round-6 verbatim.
// ---------------------------------------------------------------------------
__global__ __launch_bounds__(512, 2) void lstm_scan11(
    const int* __restrict__ x, const float* __restrict__ h0,
    const float* __restrict__ c0, const float* __restrict__ rec,
    const u16* __restrict__ xz, float* __restrict__ out,
    u32* __restrict__ fastb, u32* __restrict__ slowb) {
  extern __shared__ char sm2[];
  u16* A0 = (u16*)sm2;                 // 8 KB (4096 cells)
  u16* A1 = (u16*)(sm2 + 8192);        // 8 KB
  u32* xmask = (u32*)(sm2 + 16384);    // 1 KB [8][32]
  char* ring = sm2 + 17408;            // 8 slots * 4 KB = 32 KB
  u32* flg = (u32*)(sm2 + 50176);      // [2 parity][8 chunk]
  const int tid = threadIdx.x;
  const int wv = tid >> 6, l = tid & 63;
  const int g = blockIdx.x & 7;
  const int r = blockIdx.x >> 3;
  const int Bg = g * 8;
  const int U0 = r * 64;
  const int q = l & 3;
  const int uoff = (l >> 2) & 3;
  const int u0g = U0 + 8 * wv + uoff;
  const int u1g = u0g + 4;
  const int col0 = q * 512 + u0g;
  const int col1 = q * 512 + u1g;
  const int bl = ((l >> 4) << 2) + q;
  const int blc = bl & 7;
  const bool act = (l < 32);
  const int b = Bg + blc;
  u32* FP0 = fastb + (g * 2 + 0) * 4096;
  u32* FP1 = fastb + (g * 2 + 1) * 4096;
  u32* SP0 = slowb + (g * 2 + 0) * 4096;
  u32* SP1 = slowb + (g * 2 + 1) * 4096;

  const size_t gofs = ((size_t)(wv * 512 + U0 + l)) * BB + Bg;
  if (wv < 4) {
#pragma unroll
    for (int s = 0; s < 7; ++s)
      __builtin_amdgcn_global_load_lds(
          (AS1 const u32*)(xz + (size_t)s * GG * BB + gofs),
          (AS3 u32*)(ring + s * 4096 + wv * 1024), 16, 0, 0);
  }

  bf16x8 bfr0[16], bfr1[16];
#pragma unroll
  for (int ks = 0; ks < 16; ++ks) {
    int kbase = ks * 32 + ((l >> 4) << 3);
#pragma unroll
    for (int j = 0; j < 8; ++j) {
      bfr0[ks][j] = (short)f2bf(rec[(size_t)(kbase + j) * GG + col0]);
      bfr1[ks][j] = (short)f2bf(rec[(size_t)(kbase + j) * GG + col1]);
    }
  }
  if (tid < 256) {
    int bb = tid >> 5, tw = tid & 31;
    u32 mword = 0;
    for (int j = 0; j < 32; ++j)
      mword |= (x[(size_t)(Bg + bb) * TT + tw * 32 + j] != 0 ? 1u : 0u) << j;
    xmask[bb * 32 + tw] = mword;
  }
  if (tid < 16) flg[tid] = 0;
  float creg0 = c0[(size_t)b * HH + u0g];
  float creg1 = c0[(size_t)b * HH + u1g];
  float hreg0 = h0[(size_t)b * HH + u0g];
  float hreg1 = h0[(size_t)b * HH + u1g];
  asm volatile("s_waitcnt vmcnt(0) lgkmcnt(0)" ::: "memory");
  __syncthreads();

  {
    int uu = tid >> 3, bl2 = tid & 7;
    u32 cell = ((u32)f2bf(h0[(size_t)(Bg + bl2) * HH + U0 + uu]) << 16) | 1u;
    int wp = cellpos8(bl2, U0 + uu);
    __hip_atomic_store(&FP0[wp], cell, __ATOMIC_RELAXED,
                       __HIP_MEMORY_SCOPE_WORKGROUP);
    __hip_atomic_store(&SP0[wp], cell, __ATOMIC_RELAXED,
                       __HIP_MEMORY_SCOPE_AGENT);
  }

  const size_t OFS1 = (size_t)BB * TT * HH;
  const size_t OFS2 = OFS1 + (size_t)BB * HH;
  const int pair = (l & 7) | ((l >> 4) << 3);
  u32 mw = 0;

  for (int t = 0; t < TT; ++t) {
    // ---- 1. xz + mask from ring (independent of h) ----
    if ((t & 31) == 0) mw = xmask[blc * 32 + (t >> 5)];
    const bool m = (mw >> (t & 31)) & 1;
    const char* slab = ring + (t & 7) * 4096;
    float xzv[8];
#pragma unroll
    for (int q2 = 0; q2 < 4; ++q2) {
      xzv[q2] = bf2f(*(const u16*)(slab + q2 * 1024 + (8 * wv + uoff) * 16 +
                                   blc * 2));
      xzv[4 + q2] = bf2f(*(const u16*)(slab + q2 * 1024 +
                                       (8 * wv + uoff + 4) * 16 + blc * 2));
    }

    // ---- 2. poll OWN chunk (r6 cadence: fast, merge from try 3) ----
    const u32 expect = (u32)(t + 1) & 0xffffu;
    const u32* fb = (t & 1) ? FP1 : FP0;
    const u32* sb = (t & 1) ? SP1 : SP0;
    u32x4 v0, v1;
    LOADF(v0, fb + 8 * tid);
    LOADF(v1, fb + 8 * tid + 4);
    WAITV0;
    int tries = 0;
    while (true) {
      int bad0 = rowbad(v0, expect), bad1 = rowbad(v1, expect);
      if (!__any(bad0 | bad1)) break;
      int a0 = __any(bad0), a1 = __any(bad1);
      __builtin_amdgcn_s_sleep(1);
      ++tries;
      if (a0) LOADF(v0, fb + 8 * tid);
      if (a1) LOADF(v1, fb + 8 * tid + 4);
      if (tries >= 3) {
        u32x4 s0, s1;
        if (a0) LOADS(s0, sb + 8 * tid);
        if (a1) LOADS(s1, sb + 8 * tid + 4);
        WAITV0;
        if (a0 && !rowbad(s0, expect)) v0 = s0;
        if (a1 && !rowbad(s1, expect)) v1 = s1;
      } else {
        WAITV0;
      }
    }
    // ---- 3. strip own chunk -> A_lds, release flag ----
    u16* Ac = (t & 1) ? A1 : A0;
    {
      u32x4 dd;
      dd[0] = (v0[0] >> 16) | (v0[1] & 0xffff0000u);
      dd[1] = (v0[2] >> 16) | (v0[3] & 0xffff0000u);
      dd[2] = (v1[0] >> 16) | (v1[1] & 0xffff0000u);
      dd[3] = (v1[2] >> 16) | (v1[3] & 0xffff0000u);
      *(u32x4*)&Ac[8 * tid] = dd;
    }
    if (l == 0)
      __hip_atomic_store(&flg[(t & 1) * 8 + wv], (u32)(t + 1),
                         __ATOMIC_RELEASE, __HIP_MEMORY_SCOPE_WORKGROUP);

    // ---- 4. issue xz slab t+7 ----
    if ((t + 7 < TT) && (wv < 4))
      __builtin_amdgcn_global_load_lds(
          (AS1 const u32*)(xz + (size_t)(t + 7) * GG * BB + gofs),
          (AS3 u32*)(ring + ((t + 7) & 7) * 4096 + wv * 1024), 16, 0, 0);

    // ---- 5. chunk loop: spin flag j, MFMA (split accumulators) ----
    f32x4 a0A = {0.f, 0.f, 0.f, 0.f}, a0B = {0.f, 0.f, 0.f, 0.f};
    f32x4 a1A = {0.f, 0.f, 0.f, 0.f}, a1B = {0.f, 0.f, 0.f, 0.f};
    const u32 tagv = (u32)(t + 1);
#pragma unroll
    for (int j = 0; j < 8; ++j) {
      while (__hip_atomic_load(&flg[(t & 1) * 8 + j], __ATOMIC_ACQUIRE,
                               __HIP_MEMORY_SCOPE_WORKGROUP) != tagv)
        __builtin_amdgcn_s_sleep(1);
      bf16x8 f0 = *(const bf16x8*)&Ac[((2 * j) * 32 + pair) * 8];
      bf16x8 f1 = *(const bf16x8*)&Ac[((2 * j + 1) * 32 + pair) * 8];
      if (j & 1) {
        a0B = __builtin_amdgcn_mfma_f32_16x16x32_bf16(f0, bfr0[2 * j], a0B,
                                                      0, 0, 0);
        a0B = __builtin_amdgcn_mfma_f32_16x16x32_bf16(f1, bfr0[2 * j + 1],
                                                      a0B, 0, 0, 0);
        a1B = __builtin_amdgcn_mfma_f32_16x16x32_bf16(f0, bfr1[2 * j], a1B,
                                                      0, 0, 0);
        a1B = __builtin_amdgcn_mfma_f32_16x16x32_bf16(f1, bfr1[2 * j + 1],
                                                      a1B, 0, 0, 0);
      } else {
        a0A = __builtin_amdgcn_mfma_f32_16x16x32_bf16(f0, bfr0[2 * j], a0A,
                                                      0, 0, 0);
        a0A = __builtin_amdgcn_mfma_f32_16x16x32_bf16(f1, bfr0[2 * j + 1],
                                                      a0A, 0, 0, 0);
        a1A = __builtin_amdgcn_mfma_f32_16x16x32_bf16(f0, bfr1[2 * j], a1A,
                                                      0, 0, 0);
        a1A = __builtin_amdgcn_mfma_f32_16x16x32_bf16(f1, bfr1[2 * j + 1],
                                                      a1A, 0, 0, 0);
      }
    }
    f32x4 acc0 = a0A + a0B;
    f32x4 acc1 = a1A + a1B;

    u32* fn = (t & 1) ? FP0 : FP1;
    u32* sn = (t & 1) ? SP0 : SP1;
    const u32 ntag = (u32)(t + 2) & 0xffffu;
    float hosave[2], cosave[2];

    // ---- 6. transpose dance + gates + publish (r6 verbatim) ----
#pragma unroll
    for (int ti = 0; ti < 2; ++ti) {
      f32x4 acc = ti ? acc1 : acc0;
      float accLo = (q & 1) ? acc[1] : acc[0];
      float accHi = (q & 1) ? acc[3] : acc[2];
      float sendA = (q & 1) ? acc[0] : acc[1];
      float recvA = __shfl_xor(sendA, 1);
      float sendB = (q & 1) ? acc[2] : acc[3];
      float recvB = __shfl_xor(sendB, 1);
      float k1 = (q & 2) ? accHi : accLo;
      float s2A = (q & 2) ? accLo : accHi;
      float r2A = __shfl_xor(s2A, 2);
      float k2 = (q & 2) ? recvB : recvA;
      float s2B = (q & 2) ? recvA : recvB;
      float r2B = __shfl_xor(s2B, 2);
      float p1 = (q & 1) ? k2 : k1;
      float p2 = (q & 1) ? k1 : k2;
      float p3 = (q & 1) ? r2B : r2A;
      float p4 = (q & 1) ? r2A : r2B;
      float W0 = (q & 2) ? p3 : p1;
      float W1 = (q & 2) ? p4 : p2;
      float W2 = (q & 2) ? p1 : p3;
      float W3 = (q & 2) ? p2 : p4;
      float z0 = W0 + xzv[ti ? 4 : 0];
      float z1 = W1 + xzv[ti ? 5 : 1];
      float z2 = W2 + xzv[ti ? 6 : 2];
      float z3 = W3 + xzv[ti ? 7 : 3];
      float ig = sigm(z0), fg = sigm(z1), gg = tanhfast(z2), og = sigm(z3);
      float cprev = ti ? creg1 : creg0;
      float hprev = ti ? hreg1 : hreg0;
      float cn = fg * cprev + ig * gg;
      float hn = og * tanhfast(cn);
      float ho = m ? hn : hprev;
      float co = m ? cn : cprev;
      if (ti) { creg1 = co; hreg1 = ho; } else { creg0 = co; hreg0 = ho; }
      hosave[ti] = ho; cosave[ti] = co;
      if (act && t < TT - 1) {
        const int u = ti ? u1g : u0g;
        u32 cell = ((u32)f2bf(ho) << 16) | ntag;
        int wp = cellpos8(blc, u);
        __hip_atomic_store(&fn[wp], cell, __ATOMIC_RELAXED,
                           __HIP_MEMORY_SCOPE_WORKGROUP);
        __hip_atomic_store(&sn[wp], cell, __ATOMIC_RELAXED,
                           __HIP_MEMORY_SCOPE_AGENT);
      }
    }
    // ---- 7. outputs (r6 verbatim) ----
    if (act) {
      __builtin_nontemporal_store(hosave[0],
                                  &out[((size_t)b * TT + t) * HH + u0g]);
      __builtin_nontemporal_store(hosave[1],
                                  &out[((size_t)b * TT + t) * HH + u1g]);
      if (t == TT - 1) {
        out[OFS1 + (size_t)b * HH + u0g] = hosave[0];
        out[OFS1 + (size_t)b * HH + u1g] = hosave[1];
        out[OFS2 + (size_t)b * HH + u0g] = cosave[0];
        out[OFS2 + (size_t)b * HH + u1g] = cosave[1];
      }
    }
    // ---- 8. end-of-step barrier (LDS ping-pong reuse safety only) ----
    __builtin_amdgcn_s_barrier();
  }
}

// ---------------------------------------------------------------------------
extern "C" void kernel_launch(void* const* d_in, const int* in_sizes, int n_in,
                              void* d_out, int out_size, void* d_ws,
                              size_t ws_size, hipStream_t stream) {
  const int* x = (const int*)d_in[0];
  const float* h0 = (const float*)d_in[1];
  const float* c0 = (const float*)d_in[2];
  const float* emb = (const float*)d_in[3];
  const float* Wk = (const float*)d_in[4];
  const float* rec = (const float*)d_in[5];
  const float* bias = (const float*)d_in[6];
  float* out = (float*)d_out;
  char* ws = (char*)d_ws;

  const size_t XZ_BYTES = (size_t)TT * GG * BB * 2;      // 256 MiB
  const size_t EMBBF_BYTES = (size_t)50000 * EE * 2;     // 25.6 MB
  const size_t WKP_BYTES = (size_t)EE * GG * 2;          // 1 MB
  u16* xz = (u16*)ws;
  u32* fastb = (u32*)(ws + XZ_BYTES);            // 256 KB
  u32* slowb = (u32*)(ws + XZ_BYTES + 262144);   // 256 KB
  if (ws_size < XZ_BYTES + 524288) return;

  hipMemsetAsync(fastb, 0, 524288, stream);

  if (ws_size >= XZ_BYTES + 524288 + EMBBF_BYTES + WKP_BYTES) {
    u16* embbf = (u16*)(ws + XZ_BYTES + 524288);
    u16* wkp = (u16*)(ws + XZ_BYTES + 524288 + EMBBF_BYTES);
    conv_emb<<<12500, 256, 0, stream>>>(emb, embbf);
    pack_wk<<<256, 256, 0, stream>>>(Wk, wkp);
    hipFuncSetAttribute((const void*)xz_gemm2,
                        hipFuncAttributeMaxDynamicSharedMemorySize, 131072);
    xz_gemm2<<<512, 512, 131072, stream>>>(x, embbf, wkp, bias, xz);
  } else {
    hipFuncSetAttribute((const void*)xz_gemm_mfma,
                        hipFuncAttributeMaxDynamicSharedMemorySize, 131072);
    xz_gemm_mfma<<<TT, 256, 131072, stream>>>(x, emb, Wk, bias, xz);
  }

  hipFuncSetAttribute((const void*)lstm_scan11,
                      hipFuncAttributeMaxDynamicSharedMemorySize, 50240);
  lstm_scan11<<<64, 512, 50240, stream>>>(x, h0, c0, rec, xz, out, fastb,
                                          slowb);
}

// Round 12
// 2899.360 us; speedup vs baseline: 1.5187x; 1.1894x over previous
//
#include <hip/hip_runtime.h>
#include <stdint.h>

typedef unsigned short u16;
typedef unsigned int u32;
typedef __attribute__((ext_vector_type(8))) short bf16x8;
typedef __attribute__((ext_vector_type(4))) float f32x4;
typedef __attribute__((ext_vector_type(4))) unsigned int u32x4;
typedef __attribute__((ext_vector_type(2))) unsigned int u32x2;

#define TT 1024
#define BB 64
#define EE 256
#define HH 512
#define GG 2048   // 4H

#define AS1 __attribute__((address_space(1)))
#define AS3 __attribute__((address_space(3)))

__device__ __forceinline__ float bf2f(u16 h) {
  union { u32 i; float f; } v; v.i = ((u32)h) << 16; return v.f;
}
__device__ __forceinline__ u16 f2bf(float f) {
  union { float f; u32 i; } v; v.f = f;
  u32 b = v.i;
  return (u16)((b + 0x7fffu + ((b >> 16) & 1u)) >> 16);
}
__device__ __forceinline__ float sigm(float x) {
  return 1.f / (1.f + __expf(-x));
}
__device__ __forceinline__ float tanhfast(float x) {
  float e = __expf(2.f * x);
  return 1.f - 2.f / (e + 1.f);
}
__device__ __forceinline__ int cellpos8(int bl, int u) {
  return ((u >> 5) * 32 + ((bl & 7) | (((u >> 3) & 3) << 3))) * 8 + (u & 7);
}
__device__ __forceinline__ int rowbad(u32x4 v, u32 e) {
  return ((((v[0] ^ e) | (v[1] ^ e)) | ((v[2] ^ e) | (v[3] ^ e))) & 0xffffu)
         != 0;
}

#define LOADF(dst, ptr)                                              \
  asm volatile("global_load_dwordx4 %0, %1, off sc0"                 \
               : "=v"(dst) : "v"(ptr))
#define LOADS(dst, ptr)                                              \
  asm volatile("global_load_dwordx4 %0, %1, off sc0 sc1"             \
               : "=v"(dst) : "v"(ptr))
#define WAITV0                                                       \
  asm volatile("s_waitcnt vmcnt(0)" ::: "memory");                   \
  __builtin_amdgcn_sched_barrier(0)

// ---------------------------------------------------------------------------
// Kernel 0a: emb f32 -> bf16 (one-time). (r11-proven)
// ---------------------------------------------------------------------------
__global__ __launch_bounds__(256) void conv_emb(const float* __restrict__ emb,
                                                u16* __restrict__ embbf) {
  int i = blockIdx.x * 256 + threadIdx.x;   // 12500*256 = 3.2M quads
  float4 v = ((const float4*)emb)[i];
  u32x2 p;
  p[0] = (u32)f2bf(v.x) | ((u32)f2bf(v.y) << 16);
  p[1] = (u32)f2bf(v.z) | ((u32)f2bf(v.w) << 16);
  ((u32x2*)embbf)[i] = p;
}

// ---------------------------------------------------------------------------
// Kernel 0b: pack Wk into MFMA B-fragment order bf16. (r11-proven)
// ---------------------------------------------------------------------------
__global__ __launch_bounds__(256) void pack_wk(const float* __restrict__ Wk,
                                               u16* __restrict__ wkp) {
  int idx = blockIdx.x * 256 + threadIdx.x;   // 65536
  int ct = idx >> 9, ks = (idx >> 6) & 7, l = idx & 63;
  int col = ct * 16 + (l & 15);
  int kb = ks * 32 + ((l >> 4) << 3);
  u32x4 p;
#pragma unroll
  for (int h = 0; h < 4; ++h) {
    u16 a = f2bf(Wk[(size_t)(kb + 2 * h) * GG + col]);
    u16 b = f2bf(Wk[(size_t)(kb + 2 * h + 1) * GG + col]);
    p[h] = (u32)a | ((u32)b << 16);
  }
  *(u32x4*)&wkp[(size_t)idx * 8] = p;
}

// ---------------------------------------------------------------------------
// Kernel 1: xz GEMM from pre-packed bf16. (r11-proven, ~0.25 ms)
// ---------------------------------------------------------------------------
__global__ __launch_bounds__(512) void xz_gemm2(
    const int* __restrict__ x, const u16* __restrict__ embbf,
    const u16* __restrict__ wkp, const float* __restrict__ bias,
    u16* __restrict__ xz) {
  extern __shared__ char smg[];          // 128 KB B frags
  __shared__ int xidx[16][64];
  __shared__ float biasl[256];
  const int tid = threadIdx.x;
  const int wv = tid >> 6, l = tid & 63;
  const int cb = blockIdx.x & 7;
  const int tg = blockIdx.x >> 3;
  const int mt = wv & 3, nh = wv >> 2;

#pragma unroll
  for (int i = 0; i < 16; ++i)
    __builtin_amdgcn_global_load_lds(
        (AS1 const u32*)(wkp + ((size_t)cb * 65536) +
                         (size_t)(((i * 8 + wv) * 64) + l) * 8),
        (AS3 u32*)(smg + ((i * 8 + wv) << 10)), 16, 0, 0);
  if (tid < 256) {
    int b = tid >> 2, k4 = (tid & 3) << 2;
    int4 v = *(const int4*)&x[(size_t)b * TT + tg * 16 + k4];
    xidx[k4 + 0][b] = v.x; xidx[k4 + 1][b] = v.y;
    xidx[k4 + 2][b] = v.z; xidx[k4 + 3][b] = v.w;
    biasl[tid] = bias[cb * 256 + tid];
  }
  __syncthreads();

  const int row = mt * 16 + (l & 15);
  const int b0 = mt * 16 + ((l >> 4) << 2);
  for (int tl = 0; tl < 16; ++tl) {
    const int xid = xidx[tl][row];
    bf16x8 af[8];
#pragma unroll
    for (int ks = 0; ks < 8; ++ks)
      af[ks] = *(const bf16x8*)&embbf[(size_t)xid * EE + ks * 32 +
                                      ((l >> 4) << 3)];
    const int t = tg * 16 + tl;
#pragma unroll
    for (int nt = 0; nt < 8; ++nt) {
      const int ctl = nh * 8 + nt;
      f32x4 acc = {0.f, 0.f, 0.f, 0.f};
#pragma unroll
      for (int ks = 0; ks < 8; ++ks)
        acc = __builtin_amdgcn_mfma_f32_16x16x32_bf16(
            af[ks], *(const bf16x8*)(smg + (((ctl * 8 + ks) * 64 + l) << 4)),
            acc, 0, 0, 0);
      const int col = cb * 256 + ctl * 16 + (l & 15);
      const float bj = biasl[ctl * 16 + (l & 15)];
      u16 o0 = f2bf(acc[0] + bj), o1 = f2bf(acc[1] + bj);
      u16 o2 = f2bf(acc[2] + bj), o3 = f2bf(acc[3] + bj);
      u32* dst = (u32*)(xz + ((size_t)t * GG + col) * BB + b0);
      dst[0] = (u32)o0 | ((u32)o1 << 16);
      dst[1] = (u32)o2 | ((u32)o3 << 16);
    }
  }
}

// ---------------------------------------------------------------------------
// Kernel 1-fallback (ws too small for preconvert): rounds-3..6 gemm.
// ---------------------------------------------------------------------------
__global__ __launch_bounds__(256) void xz_gemm_mfma(
    const int* __restrict__ x, const float* __restrict__ emb,
    const float* __restrict__ Wk, const float* __restrict__ bias,
    u16* __restrict__ xz) {
  extern __shared__ char sm1[];
  bf16x8* Bl = (bf16x8*)sm1;
  __shared__ int xidx[64];
  const int tid = threadIdx.x;
  const int t = blockIdx.x;
  const int w = tid >> 6, l = tid & 63;
  if (tid < 64) xidx[tid] = x[(size_t)tid * TT + t];
  __syncthreads();
  const int row = w * 16 + (l & 15);
  const int xid = xidx[row];
  bf16x8 af[8];
#pragma unroll
  for (int ks = 0; ks < 8; ++ks) {
    int k0 = ks * 32 + ((l >> 4) << 3);
    const float4* p = (const float4*)(emb + (size_t)xid * EE + k0);
    float4 a0 = p[0], a1 = p[1];
    bf16x8 v;
    v[0] = (short)f2bf(a0.x); v[1] = (short)f2bf(a0.y);
    v[2] = (short)f2bf(a0.z); v[3] = (short)f2bf(a0.w);
    v[4] = (short)f2bf(a1.x); v[5] = (short)f2bf(a1.y);
    v[6] = (short)f2bf(a1.z); v[7] = (short)f2bf(a1.w);
    af[ks] = v;
  }
  for (int nb = 0; nb < 8; ++nb) {
    __syncthreads();
    for (int idx = tid; idx < 8192; idx += 256) {
      int nt = idx >> 9, ks = (idx >> 6) & 7, l2 = idx & 63;
      int col = nb * 256 + nt * 16 + (l2 & 15);
      int kb = ks * 32 + ((l2 >> 4) << 3);
      bf16x8 v;
#pragma unroll
      for (int j = 0; j < 8; ++j)
        v[j] = (short)f2bf(Wk[(size_t)(kb + j) * GG + col]);
      Bl[idx] = v;
    }
    __syncthreads();
#pragma unroll 2
    for (int nt = 0; nt < 16; ++nt) {
      f32x4 acc = {0.f, 0.f, 0.f, 0.f};
#pragma unroll
      for (int ks = 0; ks < 8; ++ks)
        acc = __builtin_amdgcn_mfma_f32_16x16x32_bf16(
            af[ks], Bl[(nt * 8 + ks) * 64 + l], acc, 0, 0, 0);
      int col = nb * 256 + nt * 16 + (l & 15);
      float bj = bias[col];
      int b0 = w * 16 + ((l >> 4) << 2);
      u16 o0 = f2bf(acc[0] + bj), o1 = f2bf(acc[1] + bj);
      u16 o2 = f2bf(acc[2] + bj), o3 = f2bf(acc[3] + bj);
      u32* dst = (u32*)(xz + ((size_t)t * GG + col) * BB + b0);
      dst[0] = (u32)o0 | ((u32)o1 << 16);
      dst[1] = (u32)o2 | ((u32)o3 << 16);
    }
  }
}

// ---------------------------------------------------------------------------
// Kernel 2 (round 12): round-6 scan BYTE-FOR-BYTE (the 2.68 ms kernel),
// with exactly ONE change: slow-merge onset tries>=3 -> tries>=1.
// Rationale: r6 FETCH = full stage volume every step => fast path never
// delivers (stale L2 hits); r10's onset 3->6 cost +1000 cyc/step => the
// stale rounds are pure waste; onset 1 removes ~2 of them.
// ---------------------------------------------------------------------------
__global__ __launch_bounds__(512, 2) void lstm_scan12(
    const int* __restrict__ x, const float* __restrict__ h0,
    const float* __restrict__ c0, const float* __restrict__ rec,
    const u16* __restrict__ xz, float* __restrict__ out,
    u32* __restrict__ fastb, u32* __restrict__ slowb) {
  extern __shared__ char sm2[];
  u16* A0 = (u16*)sm2;                 // 8 KB (4096 cells)
  u16* A1 = (u16*)(sm2 + 8192);        // 8 KB
  u32* xmask = (u32*)(sm2 + 16384);    // 1 KB [8][32]
  char* ring = sm2 + 17408;            // 8 slots * 4 KB = 32 KB
  const int tid = threadIdx.x;
  const int wv = tid >> 6, l = tid & 63;
  const int g = blockIdx.x & 7;
  const int r = blockIdx.x >> 3;
  const int Bg = g * 8;
  const int U0 = r * 64;
  const int q = l & 3;
  const int uoff = (l >> 2) & 3;
  const int u0g = U0 + 8 * wv + uoff;
  const int u1g = u0g + 4;
  const int col0 = q * 512 + u0g;
  const int col1 = q * 512 + u1g;
  const int bl = ((l >> 4) << 2) + q;   // 0..15, valid <8 iff l<32
  const int blc = bl & 7;
  const bool act = (l < 32);
  const int b = Bg + blc;
  u32* FP0 = fastb + (g * 2 + 0) * 4096;
  u32* FP1 = fastb + (g * 2 + 1) * 4096;
  u32* SP0 = slowb + (g * 2 + 0) * 4096;
  u32* SP1 = slowb + (g * 2 + 1) * 4096;

  // prime xz ring slots 0..6 (waves 0-3: wave wv stages gate wv, cols U0+l)
  const size_t gofs = ((size_t)(wv * 512 + U0 + l)) * BB + Bg;
  if (wv < 4) {
#pragma unroll
    for (int s = 0; s < 7; ++s)
      __builtin_amdgcn_global_load_lds(
          (AS1 const u32*)(xz + (size_t)s * GG * BB + gofs),
          (AS3 u32*)(ring + s * 4096 + wv * 1024), 16, 0, 0);
  }

  // --- B fragments (R slice) into registers, once ---
  bf16x8 bfr0[16], bfr1[16];
#pragma unroll
  for (int ks = 0; ks < 16; ++ks) {
    int kbase = ks * 32 + ((l >> 4) << 3);
#pragma unroll
    for (int j = 0; j < 8; ++j) {
      bfr0[ks][j] = (short)f2bf(rec[(size_t)(kbase + j) * GG + col0]);
      bfr1[ks][j] = (short)f2bf(rec[(size_t)(kbase + j) * GG + col1]);
    }
  }
  // --- x bitmask for group's 8 batches ---
  if (tid < 256) {
    int bb = tid >> 5, tw = tid & 31;
    u32 mword = 0;
    for (int j = 0; j < 32; ++j)
      mword |= (x[(size_t)(Bg + bb) * TT + tw * 32 + j] != 0 ? 1u : 0u) << j;
    xmask[bb * 32 + tw] = mword;
  }
  float creg0 = c0[(size_t)b * HH + u0g];
  float creg1 = c0[(size_t)b * HH + u1g];
  float hreg0 = h0[(size_t)b * HH + u0g];
  float hreg1 = h0[(size_t)b * HH + u1g];
  // drain prime glls + loads before barrier
  asm volatile("s_waitcnt vmcnt(0) lgkmcnt(0)" ::: "memory");
  __syncthreads();

  // --- publish h(0): 512 cells/WG, tag 1, dual copy ---
  {
    int uu = tid >> 3, bl2 = tid & 7;
    u32 cell = ((u32)f2bf(h0[(size_t)(Bg + bl2) * HH + U0 + uu]) << 16) | 1u;
    int wp = cellpos8(bl2, U0 + uu);
    __hip_atomic_store(&FP0[wp], cell, __ATOMIC_RELAXED,
                       __HIP_MEMORY_SCOPE_WORKGROUP);
    __hip_atomic_store(&SP0[wp], cell, __ATOMIC_RELAXED,
                       __HIP_MEMORY_SCOPE_AGENT);
  }

  const size_t OFS1 = (size_t)BB * TT * HH;
  const size_t OFS2 = OFS1 + (size_t)BB * HH;
  const int pair = (l & 7) | ((l >> 4) << 3);
  u32 mw = 0;

  for (int t = 0; t < TT; ++t) {
    // ---- 1. xz + mask for this step from ring (independent of h) ----
    if ((t & 31) == 0) mw = xmask[blc * 32 + (t >> 5)];
    const bool m = (mw >> (t & 31)) & 1;
    const char* slab = ring + (t & 7) * 4096;
    float xzv[8];
#pragma unroll
    for (int q2 = 0; q2 < 4; ++q2) {
      xzv[q2] = bf2f(*(const u16*)(slab + q2 * 1024 + (8 * wv + uoff) * 16 +
                                   blc * 2));
      xzv[4 + q2] = bf2f(*(const u16*)(slab + q2 * 1024 +
                                       (8 * wv + uoff + 4) * 16 + blc * 2));
    }

    // ---- 2. stage h(t): fast probe, slow merge from try 1 ----
    const u32 expect = (u32)(t + 1) & 0xffffu;
    const u32* fb = (t & 1) ? FP1 : FP0;
    const u32* sb = (t & 1) ? SP1 : SP0;
    u32x4 v0, v1;
    LOADF(v0, fb + 8 * tid);
    LOADF(v1, fb + 8 * tid + 4);
    WAITV0;
    int tries = 0;
    while (true) {
      int bad0 = rowbad(v0, expect), bad1 = rowbad(v1, expect);
      if (!__any(bad0 | bad1)) break;
      int a0 = __any(bad0), a1 = __any(bad1);
      __builtin_amdgcn_s_sleep(1);
      ++tries;
      if (a0) LOADF(v0, fb + 8 * tid);
      if (a1) LOADF(v1, fb + 8 * tid + 4);
      if (tries >= 1) {
        u32x4 s0, s1;
        if (a0) LOADS(s0, sb + 8 * tid);
        if (a1) LOADS(s1, sb + 8 * tid + 4);
        WAITV0;
        if (a0 && !rowbad(s0, expect)) v0 = s0;
        if (a1 && !rowbad(s1, expect)) v1 = s1;
      } else {
        WAITV0;
      }
    }
    // ---- 3. strip tags -> ping-pong A_lds; one barrier ----
    u16* Ac = (t & 1) ? A1 : A0;
    {
      u32x4 dd;
      dd[0] = (v0[0] >> 16) | (v0[1] & 0xffff0000u);
      dd[1] = (v0[2] >> 16) | (v0[3] & 0xffff0000u);
      dd[2] = (v1[0] >> 16) | (v1[1] & 0xffff0000u);
      dd[3] = (v1[2] >> 16) | (v1[3] & 0xffff0000u);
      *(u32x4*)&Ac[8 * tid] = dd;
    }
    asm volatile("s_waitcnt lgkmcnt(0)" ::: "memory");
    __builtin_amdgcn_s_barrier();
    __builtin_amdgcn_sched_barrier(0);

    // ---- 4. issue xz slab t+7 ----
    if ((t + 7 < TT) && (wv < 4))
      __builtin_amdgcn_global_load_lds(
          (AS1 const u32*)(xz + (size_t)(t + 7) * GG * BB + gofs),
          (AS3 u32*)(ring + ((t + 7) & 7) * 4096 + wv * 1024), 16, 0, 0);

    // ---- 5. A frags + MFMA ----
    bf16x8 af[16];
#pragma unroll
    for (int ks = 0; ks < 16; ++ks)
      af[ks] = *(const bf16x8*)&Ac[(ks * 32 + pair) * 8];
    f32x4 acc0 = {0.f, 0.f, 0.f, 0.f}, acc1 = {0.f, 0.f, 0.f, 0.f};
#pragma unroll
    for (int ks = 0; ks < 16; ++ks) {
      acc0 = __builtin_amdgcn_mfma_f32_16x16x32_bf16(af[ks], bfr0[ks], acc0,
                                                     0, 0, 0);
      acc1 = __builtin_amdgcn_mfma_f32_16x16x32_bf16(af[ks], bfr1[ks], acc1,
                                                     0, 0, 0);
    }

    u32* fn = (t & 1) ? FP0 : FP1;
    u32* sn = (t & 1) ? SP0 : SP1;
    const u32 ntag = (u32)(t + 2) & 0xffffu;
    float hosave[2], cosave[2];

    // ---- 6. transpose dance + gates + publish (r6 verbatim) ----
#pragma unroll
    for (int ti = 0; ti < 2; ++ti) {
      f32x4 acc = ti ? acc1 : acc0;
      float accLo = (q & 1) ? acc[1] : acc[0];
      float accHi = (q & 1) ? acc[3] : acc[2];
      float sendA = (q & 1) ? acc[0] : acc[1];
      float recvA = __shfl_xor(sendA, 1);
      float sendB = (q & 1) ? acc[2] : acc[3];
      float recvB = __shfl_xor(sendB, 1);
      float k1 = (q & 2) ? accHi : accLo;
      float s2A = (q & 2) ? accLo : accHi;
      float r2A = __shfl_xor(s2A, 2);
      float k2 = (q & 2) ? recvB : recvA;
      float s2B = (q & 2) ? recvA : recvB;
      float r2B = __shfl_xor(s2B, 2);
      float p1 = (q & 1) ? k2 : k1;
      float p2 = (q & 1) ? k1 : k2;
      float p3 = (q & 1) ? r2B : r2A;
      float p4 = (q & 1) ? r2A : r2B;
      float W0 = (q & 2) ? p3 : p1;
      float W1 = (q & 2) ? p4 : p2;
      float W2 = (q & 2) ? p1 : p3;
      float W3 = (q & 2) ? p2 : p4;
      float z0 = W0 + xzv[ti ? 4 : 0];
      float z1 = W1 + xzv[ti ? 5 : 1];
      float z2 = W2 + xzv[ti ? 6 : 2];
      float z3 = W3 + xzv[ti ? 7 : 3];
      float ig = sigm(z0), fg = sigm(z1), gg = tanhfast(z2), og = sigm(z3);
      float cprev = ti ? creg1 : creg0;
      float hprev = ti ? hreg1 : hreg0;
      float cn = fg * cprev + ig * gg;
      float hn = og * tanhfast(cn);
      float ho = m ? hn : hprev;
      float co = m ? cn : cprev;
      if (ti) { creg1 = co; hreg1 = ho; } else { creg0 = co; hreg0 = ho; }
      hosave[ti] = ho; cosave[ti] = co;
      // publish immediately (critical path): dual copy
      if (act && t < TT - 1) {
        const int u = ti ? u1g : u0g;
        u32 cell = ((u32)f2bf(ho) << 16) | ntag;
        int wp = cellpos8(blc, u);
        __hip_atomic_store(&fn[wp], cell, __ATOMIC_RELAXED,
                           __HIP_MEMORY_SCOPE_WORKGROUP);
        __hip_atomic_store(&sn[wp], cell, __ATOMIC_RELAXED,
                           __HIP_MEMORY_SCOPE_AGENT);
      }
    }
    // ---- 7. outputs (r6 verbatim) ----
    if (act) {
      __builtin_nontemporal_store(hosave[0],
                                  &out[((size_t)b * TT + t) * HH + u0g]);
      __builtin_nontemporal_store(hosave[1],
                                  &out[((size_t)b * TT + t) * HH + u1g]);
      if (t == TT - 1) {
        out[OFS1 + (size_t)b * HH + u0g] = hosave[0];
        out[OFS1 + (size_t)b * HH + u1g] = hosave[1];
        out[OFS2 + (size_t)b * HH + u0g] = cosave[0];
        out[OFS2 + (size_t)b * HH + u1g] = cosave[1];
      }
    }
  }
}

// ---------------------------------------------------------------------------
extern "C" void kernel_launch(void* const* d_in, const int* in_sizes, int n_in,
                              void* d_out, int out_size, void* d_ws,
                              size_t ws_size, hipStream_t stream) {
  const int* x = (const int*)d_in[0];
  const float* h0 = (const float*)d_in[1];
  const float* c0 = (const float*)d_in[2];
  const float* emb = (const float*)d_in[3];
  const float* Wk = (const float*)d_in[4];
  const float* rec = (const float*)d_in[5];
  const float* bias = (const float*)d_in[6];
  float* out = (float*)d_out;
  char* ws = (char*)d_ws;

  const size_t XZ_BYTES = (size_t)TT * GG * BB * 2;      // 256 MiB
  const size_t EMBBF_BYTES = (size_t)50000 * EE * 2;     // 25.6 MB
  const size_t WKP_BYTES = (size_t)EE * GG * 2;          // 1 MB
  u16* xz = (u16*)ws;
  u32* fastb = (u32*)(ws + XZ_BYTES);            // 256 KB
  u32* slowb = (u32*)(ws + XZ_BYTES + 262144);   // 256 KB
  if (ws_size < XZ_BYTES + 524288) return;

  hipMemsetAsync(fastb, 0, 524288, stream);

  if (ws_size >= XZ_BYTES + 524288 + EMBBF_BYTES + WKP_BYTES) {
    u16* embbf = (u16*)(ws + XZ_BYTES + 524288);
    u16* wkp = (u16*)(ws + XZ_BYTES + 524288 + EMBBF_BYTES);
    conv_emb<<<12500, 256, 0, stream>>>(emb, embbf);
    pack_wk<<<256, 256, 0, stream>>>(Wk, wkp);
    hipFuncSetAttribute((const void*)xz_gemm2,
                        hipFuncAttributeMaxDynamicSharedMemorySize, 131072);
    xz_gemm2<<<512, 512, 131072, stream>>>(x, embbf, wkp, bias, xz);
  } else {
    hipFuncSetAttribute((const void*)xz_gemm_mfma,
                        hipFuncAttributeMaxDynamicSharedMemorySize, 131072);
    xz_gemm_mfma<<<TT, 256, 131072, stream>>>(x, emb, Wk, bias, xz);
  }

  hipFuncSetAttribute((const void*)lstm_scan12,
                      hipFuncAttributeMaxDynamicSharedMemorySize, 50176);
  lstm_scan12<<<64, 512, 50176, stream>>>(x, h0, c0, rec, xz, out, fastb,
                                          slowb);
}